// Round 3
// baseline (619.795 us; speedup 1.0000x reference)
//
#include <hip/hip_runtime.h>
#include <hip/hip_bf16.h>
#include <math.h>

#define B_   64
#define N_   100
#define K_   16
#define C_   1024
#define R_   8
#define D_   128
#define BN_  (B_*N_)    // 6400
#define E_   (BN_*K_)   // 102400

// --------------------------------------------------------------------------
// Edge weights for both layers.
// --------------------------------------------------------------------------
__global__ __launch_bounds__(256) void edge_weights_kernel(
        const float* __restrict__ centre,   // [BN,2]
        const int*   __restrict__ nbr_idx,  // [BN,K]
        const float* __restrict__ graph_w,  // [E,1]
        const float* __restrict__ mr1, const float* __restrict__ mt1,
        const float* __restrict__ pr1, const float* __restrict__ pt1,
        const float* __restrict__ mr2, const float* __restrict__ mt2,
        const float* __restrict__ pr2, const float* __restrict__ pt2,
        float* __restrict__ w1, float* __restrict__ w2) {
    int e = blockIdx.x * blockDim.x + threadIdx.x;
    if (e >= E_) return;
    int n = e / K_;
    int b = n / N_;
    int nbr = nbr_idx[e];
    int fn = b * N_ + nbr;
    float dx = centre[2*n]   - centre[2*fn];
    float dy = centre[2*n+1] - centre[2*fn+1];
    float rho   = sqrtf(dx*dx + dy*dy);
    float theta = atan2f(dx, dy);           // reference order arctan2(d0, d1)
    const float TWO_PI = 6.28318530717958647692f;

    // ---- layer 1 ----
    {
        float w[R_]; float s = 0.f;
        #pragma unroll
        for (int r = 0; r < R_; ++r) {
            float dr = rho - mr1[r];
            float wr = expf(-0.5f * dr * dr / (1e-14f + pr1[r]*pr1[r]));
            float fa = fabsf(theta - mt1[r]);
            float sa = fabsf(TWO_PI - fa);
            float mi = fminf(fa, sa);
            float wt = expf(-0.5f * mi * mi / (1e-14f + pt1[r]*pt1[r]));
            float ww = wr * wt;
            if (isnan(ww)) ww = 0.f;
            w[r] = ww; s += ww;
        }
        float gw = graph_w[e];
        #pragma unroll
        for (int r = 0; r < R_; ++r) w1[e*R_ + r] = gw * (w[r] / s);
    }
    // ---- layer 2 ----
    {
        float w[R_]; float s = 0.f;
        #pragma unroll
        for (int r = 0; r < R_; ++r) {
            float dr = rho - mr2[r];
            float wr = expf(-0.5f * dr * dr / (1e-14f + pr2[r]*pr2[r]));
            float fa = fabsf(theta - mt2[r]);
            float sa = fabsf(TWO_PI - fa);
            float mi = fminf(fa, sa);
            float wt = expf(-0.5f * mi * mi / (1e-14f + pt2[r]*pt2[r]));
            float ww = wr * wt;
            if (isnan(ww)) ww = 0.f;
            w[r] = ww; s += ww;
        }
        #pragma unroll
        for (int r = 0; r < R_; ++r) w2[e*R_ + r] = w[r] / s;
    }
}

// --------------------------------------------------------------------------
// proj[m, j] = sum_c X[m,c] * Wc[j>>7, c, j&127];  M=6400, N=1024, K=1024.
// 64x64 tile / 256 threads / 4x4 per thread, fp32.
// --------------------------------------------------------------------------
#define TM 64
#define TN 64
#define TK 16

__global__ __launch_bounds__(256) void gemm_proj_kernel(
        const float* __restrict__ X,     // [BN, 1024]
        const float* __restrict__ Wc,    // [8, 1024, 128]
        float* __restrict__ P) {         // [BN, 1024]
    __shared__ float As[TK][TM + 1];
    __shared__ float Bs[TK][TN];
    int m0 = blockIdx.y * TM;
    int n0 = blockIdx.x * TN;
    int t  = threadIdx.x;
    int tx = t & 15, ty = t >> 4;
    float acc[4][4] = {};
    for (int c0 = 0; c0 < C_; c0 += TK) {
        #pragma unroll
        for (int i = 0; i < 4; ++i) {
            int idx = t + i * 256;
            int mm = idx >> 4, kk = idx & 15;
            As[kk][mm] = X[(m0 + mm) * C_ + c0 + kk];
        }
        #pragma unroll
        for (int i = 0; i < 4; ++i) {
            int idx = t + i * 256;
            int nn = idx & 63, kk = idx >> 6;
            int j  = n0 + nn;
            int c  = c0 + kk;
            Bs[kk][nn] = Wc[(((j >> 7) << 10) + c) * 128 + (j & 127)];
        }
        __syncthreads();
        #pragma unroll
        for (int kk = 0; kk < TK; ++kk) {
            float a[4], bv[4];
            #pragma unroll
            for (int i = 0; i < 4; ++i) a[i]  = As[kk][ty*4 + i];
            #pragma unroll
            for (int j = 0; j < 4; ++j) bv[j] = Bs[kk][tx*4 + j];
            #pragma unroll
            for (int i = 0; i < 4; ++i)
                #pragma unroll
                for (int j = 0; j < 4; ++j)
                    acc[i][j] += a[i] * bv[j];
        }
        __syncthreads();
    }
    #pragma unroll
    for (int i = 0; i < 4; ++i) {
        int m = m0 + ty*4 + i;
        #pragma unroll
        for (int j = 0; j < 4; ++j)
            P[m * 1024 + n0 + tx*4 + j] = acc[i][j];
    }
}

// --------------------------------------------------------------------------
// out[n, j] = relu( sum_k w[n*K+k, j>>7] * P[fnbr(n,k)*1024 + j] )   (fp32 out)
// --------------------------------------------------------------------------
__global__ __launch_bounds__(256) void aggregate_kernel(
        const float* __restrict__ P,        // [BN, 1024]
        const float* __restrict__ w,        // [E, 8]
        const int*   __restrict__ nbr_idx,  // [BN, K]
        float* __restrict__ out) {          // [BN, 1024] fp32
    __shared__ float wv[K_][R_];
    __shared__ int   fnbr[K_];
    int n = blockIdx.x;
    int t = threadIdx.x;
    if (t < K_ * R_) {
        int k = t >> 3, r = t & 7;
        wv[k][r] = w[(n * K_ + k) * R_ + r];
    }
    if (t < K_) {
        int b = n / N_;
        fnbr[t] = b * N_ + nbr_idx[n * K_ + t];
    }
    __syncthreads();
    #pragma unroll
    for (int jj = 0; jj < 4; ++jj) {
        int j = t + jj * 256;
        int r = j >> 7;
        float acc = 0.f;
        #pragma unroll
        for (int k = 0; k < K_; ++k)
            acc += wv[k][r] * P[fnbr[k] * 1024 + j];
        out[n * 1024 + j] = fmaxf(acc, 0.f);
    }
}

// --------------------------------------------------------------------------
extern "C" void kernel_launch(void* const* d_in, const int* in_sizes, int n_in,
                              void* d_out, int out_size, void* d_ws, size_t ws_size,
                              hipStream_t stream) {
    const float* node_feats = (const float*)d_in[0];
    const float* centre     = (const float*)d_in[1];
    const float* graph_w    = (const float*)d_in[2];
    const int*   nbr_idx    = (const int*)  d_in[3];
    const float* mr1 = (const float*)d_in[4];
    const float* mt1 = (const float*)d_in[5];
    const float* pr1 = (const float*)d_in[6];
    const float* pt1 = (const float*)d_in[7];
    const float* cw1 = (const float*)d_in[8];
    const float* mr2 = (const float*)d_in[9];
    const float* mt2 = (const float*)d_in[10];
    const float* pr2 = (const float*)d_in[11];
    const float* pt2 = (const float*)d_in[12];
    const float* cw2 = (const float*)d_in[13];

    float* w1   = (float*)d_ws;              // [E,8]
    float* w2   = w1 + (size_t)E_ * R_;      // [E,8]
    float* bufA = w2 + (size_t)E_ * R_;      // [BN,1024] proj1 then proj2
    float* bufB = bufA + (size_t)BN_ * 1024; // [BN,1024] h (layer-1 output)

    float* out = (float*)d_out;              // reference output dtype is fp32

    edge_weights_kernel<<<(E_ + 255) / 256, 256, 0, stream>>>(
        centre, nbr_idx, graph_w, mr1, mt1, pr1, pt1, mr2, mt2, pr2, pt2, w1, w2);

    gemm_proj_kernel<<<dim3(16, 100), 256, 0, stream>>>(node_feats, cw1, bufA);
    aggregate_kernel<<<BN_, 256, 0, stream>>>(bufA, w1, nbr_idx, bufB);

    gemm_proj_kernel<<<dim3(16, 100), 256, 0, stream>>>(bufB, cw2, bufA);
    aggregate_kernel<<<BN_, 256, 0, stream>>>(bufA, w2, nbr_idx, out);
}

// Round 5
// 201.589 us; speedup vs baseline: 3.0745x; 3.0745x over previous
//
#include <hip/hip_runtime.h>
#include <hip/hip_bf16.h>
#include <math.h>

#define B_   64
#define N_   100
#define K_   16
#define C_   1024
#define R_   8
#define BN_  6400
#define E_   102400

typedef __attribute__((ext_vector_type(8))) short bf16x8;
typedef __attribute__((ext_vector_type(4))) float f32x4;

__device__ __forceinline__ float bf2f(ushort h) {
    union { uint32_t u; float f; } v; v.u = ((uint32_t)h) << 16; return v.f;
}
__device__ __forceinline__ ushort f2bf(float f) {
    union { float f; uint32_t u; } v; v.f = f;
    uint32_t r = v.u + 0x7FFFu + ((v.u >> 16) & 1u);   // RNE
    return (ushort)(r >> 16);
}

__device__ __forceinline__ void gload_lds16(const void* g, void* l) {
    __builtin_amdgcn_global_load_lds(
        (const __attribute__((address_space(1))) void*)g,
        (__attribute__((address_space(3))) void*)l, 16, 0, 0);
}

// --------------------------------------------------------------------------
// Edge weights for both layers (fp32, exact mirror of reference math).
// --------------------------------------------------------------------------
__global__ __launch_bounds__(256) void edge_weights_kernel(
        const float* __restrict__ centre, const int* __restrict__ nbr_idx,
        const float* __restrict__ graph_w,
        const float* __restrict__ mr1, const float* __restrict__ mt1,
        const float* __restrict__ pr1, const float* __restrict__ pt1,
        const float* __restrict__ mr2, const float* __restrict__ mt2,
        const float* __restrict__ pr2, const float* __restrict__ pt2,
        float* __restrict__ w1, float* __restrict__ w2) {
    int e = blockIdx.x * blockDim.x + threadIdx.x;
    if (e >= E_) return;
    int n = e / K_;
    int b = n / N_;
    int fn = b * N_ + nbr_idx[e];
    float dx = centre[2*n]   - centre[2*fn];
    float dy = centre[2*n+1] - centre[2*fn+1];
    float rho   = sqrtf(dx*dx + dy*dy);
    float theta = atan2f(dx, dy);
    const float TWO_PI = 6.28318530717958647692f;
    {
        float w[R_]; float s = 0.f;
        #pragma unroll
        for (int r = 0; r < R_; ++r) {
            float dr = rho - mr1[r];
            float wr = expf(-0.5f * dr * dr / (1e-14f + pr1[r]*pr1[r]));
            float fa = fabsf(theta - mt1[r]);
            float mi = fminf(fa, fabsf(TWO_PI - fa));
            float wt = expf(-0.5f * mi * mi / (1e-14f + pt1[r]*pt1[r]));
            float ww = wr * wt;
            if (isnan(ww)) ww = 0.f;
            w[r] = ww; s += ww;
        }
        float gw = graph_w[e];
        #pragma unroll
        for (int r = 0; r < R_; ++r) w1[e*R_ + r] = gw * (w[r] / s);
    }
    {
        float w[R_]; float s = 0.f;
        #pragma unroll
        for (int r = 0; r < R_; ++r) {
            float dr = rho - mr2[r];
            float wr = expf(-0.5f * dr * dr / (1e-14f + pr2[r]*pr2[r]));
            float fa = fabsf(theta - mt2[r]);
            float mi = fminf(fa, fabsf(TWO_PI - fa));
            float wt = expf(-0.5f * mi * mi / (1e-14f + pt2[r]*pt2[r]));
            float ww = wr * wt;
            if (isnan(ww)) ww = 0.f;
            w[r] = ww; s += ww;
        }
        #pragma unroll
        for (int r = 0; r < R_; ++r) w2[e*R_ + r] = w[r] / s;
    }
}

// --------------------------------------------------------------------------
// X fp32 -> bf16 (vectorized)
// --------------------------------------------------------------------------
__global__ __launch_bounds__(256) void cast_x_kernel(
        const float* __restrict__ X, ushort* __restrict__ Xb) {
    int i = (blockIdx.x * 256 + threadIdx.x) * 4;
    float4 v = *(const float4*)&X[i];
    ushort4 o; o.x = f2bf(v.x); o.y = f2bf(v.y); o.z = f2bf(v.z); o.w = f2bf(v.w);
    *(ushort4*)&Xb[i] = o;
}

// --------------------------------------------------------------------------
// conv_w [8][1024][128] fp32  ->  Wt [1024(j)][1024(c)] bf16, Wt[j][c]=W[j>>7][c][j&127]
// --------------------------------------------------------------------------
__global__ __launch_bounds__(256) void wtrans_kernel(
        const float* __restrict__ W, ushort* __restrict__ Wt) {
    int j = blockIdx.x;
    int c = blockIdx.y * 256 + threadIdx.x;
    float v = W[((j >> 7) << 17) + c * 128 + (j & 127)];
    Wt[j * 1024 + c] = f2bf(v);
}

// --------------------------------------------------------------------------
// bf16 MFMA GEMM: P[m][j] = sum_c Xb[m][c] * Wt[j][c].  M=6400,N=1024,K=1024.
// 128x128 tile, BK=32, 4 waves, 16x16x32 MFMA, global_load_lds w=16,
// LDS 16B-slot XOR swizzle (pre-swizzled source + swizzled read).
// --------------------------------------------------------------------------
__global__ __launch_bounds__(256) void gemm_bf16_kernel(
        const ushort* __restrict__ Xb,   // [6400][1024]
        const ushort* __restrict__ Wt,   // [1024][1024]
        ushort* __restrict__ P) {        // [6400][1024]
    __shared__ ushort As[128][32];
    __shared__ ushort Bs[128][32];
    int tile = blockIdx.x;                       // 400 = 8 XCDs * 50
    int swz  = (tile & 7) * 50 + (tile >> 3);    // bijective XCD chunking
    int m0 = (swz >> 3) * 128, n0 = (swz & 7) * 128;
    int t = threadIdx.x, wid = t >> 6, lane = t & 63;
    int wr = wid >> 1, wc = wid & 1;

    // staging: lane -> row lane>>2 (of 16-row chunk), source slot pre-swizzled
    int srow  = lane >> 2;
    int sslot = (lane & 3) ^ ((lane >> 2) & 3) ^ (lane >> 4);
    // fragment read: physical 16B slot for this lane (same involution)
    int pslot = (lane >> 4) ^ (lane & 3) ^ ((lane >> 2) & 3);

    f32x4 acc[4][4];
    #pragma unroll
    for (int i = 0; i < 4; ++i)
        #pragma unroll
        for (int j = 0; j < 4; ++j) acc[i][j] = (f32x4)0.f;

    int arow = wr * 64 + (lane & 15);
    int brow = wc * 64 + (lane & 15);

    for (int c0 = 0; c0 < 1024; c0 += 32) {
        #pragma unroll
        for (int q = 0; q < 2; ++q) {
            int rowblk = (q * 4 + wid) * 16;     // wave-uniform LDS base
            gload_lds16(Xb + (size_t)(m0 + rowblk + srow) * 1024 + c0 + sslot * 8,
                        &As[rowblk][0]);
            gload_lds16(Wt + (size_t)(n0 + rowblk + srow) * 1024 + c0 + sslot * 8,
                        &Bs[rowblk][0]);
        }
        __syncthreads();
        bf16x8 af[4], bfr[4];
        #pragma unroll
        for (int mi = 0; mi < 4; ++mi)
            af[mi] = *(const bf16x8*)&As[arow + mi * 16][pslot * 8];
        #pragma unroll
        for (int ni = 0; ni < 4; ++ni)
            bfr[ni] = *(const bf16x8*)&Bs[brow + ni * 16][pslot * 8];
        #pragma unroll
        for (int mi = 0; mi < 4; ++mi)
            #pragma unroll
            for (int ni = 0; ni < 4; ++ni)
                acc[mi][ni] = __builtin_amdgcn_mfma_f32_16x16x32_bf16(
                    af[mi], bfr[ni], acc[mi][ni], 0, 0, 0);
        __syncthreads();
    }
    // C/D: col = lane&15, row = (lane>>4)*4 + q   [m89-verified]
    int col = lane & 15, rq = lane >> 4;
    #pragma unroll
    for (int mi = 0; mi < 4; ++mi) {
        int row = m0 + wr * 64 + mi * 16 + rq * 4;
        #pragma unroll
        for (int ni = 0; ni < 4; ++ni) {
            int cc = n0 + wc * 64 + ni * 16 + col;
            #pragma unroll
            for (int q = 0; q < 4; ++q)
                P[(size_t)(row + q) * 1024 + cc] = f2bf(acc[mi][ni][q]);
        }
    }
}

// --------------------------------------------------------------------------
// out[n,j] = relu( sum_k w[nK+k, j>>7] * P[fnbr(n,k)][j] ); P bf16.
// outB (bf16 h) or outF (fp32 final).
// --------------------------------------------------------------------------
__global__ __launch_bounds__(256) void aggregate_kernel(
        const ushort* __restrict__ P, const float* __restrict__ w,
        const int* __restrict__ nbr_idx,
        ushort* __restrict__ outB, float* __restrict__ outF) {
    __shared__ float wv[K_][R_];
    __shared__ int fnbr[K_];
    int bid = blockIdx.x;                    // 6400 = 8 * 800, bijective
    int n = (bid & 7) * 800 + (bid >> 3);
    int t = threadIdx.x;
    if (t < K_ * R_) { int k = t >> 3, r = t & 7; wv[k][r] = w[(n * K_ + k) * R_ + r]; }
    if (t < K_) fnbr[t] = (n / N_) * N_ + nbr_idx[n * K_ + t];
    __syncthreads();
    int j0 = t * 4;
    int r = t >> 5;                          // (t*4)>>7
    float a0 = 0.f, a1 = 0.f, a2 = 0.f, a3 = 0.f;
    #pragma unroll
    for (int k = 0; k < K_; ++k) {
        ushort4 v = *(const ushort4*)&P[(size_t)fnbr[k] * 1024 + j0];
        float wk = wv[k][r];
        a0 += wk * bf2f(v.x); a1 += wk * bf2f(v.y);
        a2 += wk * bf2f(v.z); a3 += wk * bf2f(v.w);
    }
    a0 = fmaxf(a0, 0.f); a1 = fmaxf(a1, 0.f);
    a2 = fmaxf(a2, 0.f); a3 = fmaxf(a3, 0.f);
    if (outB) {
        ushort4 o; o.x = f2bf(a0); o.y = f2bf(a1); o.z = f2bf(a2); o.w = f2bf(a3);
        *(ushort4*)&outB[(size_t)n * 1024 + j0] = o;
    } else {
        float4 o; o.x = a0; o.y = a1; o.z = a2; o.w = a3;
        *(float4*)&outF[(size_t)n * 1024 + j0] = o;
    }
}

// --------------------------------------------------------------------------
extern "C" void kernel_launch(void* const* d_in, const int* in_sizes, int n_in,
                              void* d_out, int out_size, void* d_ws, size_t ws_size,
                              hipStream_t stream) {
    const float* node_feats = (const float*)d_in[0];
    const float* centre     = (const float*)d_in[1];
    const float* graph_w    = (const float*)d_in[2];
    const int*   nbr_idx    = (const int*)  d_in[3];
    const float* mr1 = (const float*)d_in[4];
    const float* mt1 = (const float*)d_in[5];
    const float* pr1 = (const float*)d_in[6];
    const float* pt1 = (const float*)d_in[7];
    const float* cw1 = (const float*)d_in[8];
    const float* mr2 = (const float*)d_in[9];
    const float* mt2 = (const float*)d_in[10];
    const float* pr2 = (const float*)d_in[11];
    const float* pt2 = (const float*)d_in[12];
    const float* cw2 = (const float*)d_in[13];

    char* ws = (char*)d_ws;
    float*  w1  = (float*)ws;                 ws += (size_t)E_ * R_ * 4;   // 3.28 MB
    float*  w2  = (float*)ws;                 ws += (size_t)E_ * R_ * 4;   // 3.28 MB
    ushort* Xb  = (ushort*)ws;                ws += (size_t)BN_ * 1024 * 2; // 13.1 MB
    ushort* W1t = (ushort*)ws;                ws += (size_t)1024 * 1024 * 2;
    ushort* W2t = (ushort*)ws;                ws += (size_t)1024 * 1024 * 2;
    ushort* hb  = (ushort*)ws;                ws += (size_t)BN_ * 1024 * 2; // 13.1 MB
    ushort* P   = (ushort*)ws;                                            // 13.1 MB

    float* out = (float*)d_out;

    edge_weights_kernel<<<(E_ + 255) / 256, 256, 0, stream>>>(
        centre, nbr_idx, graph_w, mr1, mt1, pr1, pt1, mr2, mt2, pr2, pt2, w1, w2);
    cast_x_kernel<<<BN_ * 1024 / 4 / 256, 256, 0, stream>>>(node_feats, Xb);
    wtrans_kernel<<<dim3(1024, 4), 256, 0, stream>>>(cw1, W1t);
    wtrans_kernel<<<dim3(1024, 4), 256, 0, stream>>>(cw2, W2t);

    gemm_bf16_kernel<<<400, 256, 0, stream>>>(Xb, W1t, P);
    aggregate_kernel<<<BN_, 256, 0, stream>>>(P, w1, nbr_idx, hb, nullptr);

    gemm_bf16_kernel<<<400, 256, 0, stream>>>(hb, W2t, P);
    aggregate_kernel<<<BN_, 256, 0, stream>>>(P, w2, nbr_idx, nullptr, out);
}

// Round 6
// 192.477 us; speedup vs baseline: 3.2201x; 1.0473x over previous
//
#include <hip/hip_runtime.h>
#include <hip/hip_bf16.h>
#include <math.h>

#define B_   64
#define N_   100
#define K_   16
#define C_   1024
#define R_   8
#define BN_  6400
#define E_   102400

typedef __attribute__((ext_vector_type(8))) short bf16x8;
typedef __attribute__((ext_vector_type(4))) float f32x4;

__device__ __forceinline__ float bf2f(ushort h) {
    union { uint32_t u; float f; } v; v.u = ((uint32_t)h) << 16; return v.f;
}
__device__ __forceinline__ ushort f2bf(float f) {
    union { float f; uint32_t u; } v; v.f = f;
    uint32_t r = v.u + 0x7FFFu + ((v.u >> 16) & 1u);   // RNE
    return (ushort)(r >> 16);
}

__device__ __forceinline__ void gload_lds16(const void* g, void* l) {
    __builtin_amdgcn_global_load_lds(
        (const __attribute__((address_space(1))) void*)g,
        (__attribute__((address_space(3))) void*)l, 16, 0, 0);
}

// --------------------------------------------------------------------------
// Edge weights for both layers (fp32, exact mirror of reference math).
// --------------------------------------------------------------------------
__global__ __launch_bounds__(256) void edge_weights_kernel(
        const float* __restrict__ centre, const int* __restrict__ nbr_idx,
        const float* __restrict__ graph_w,
        const float* __restrict__ mr1, const float* __restrict__ mt1,
        const float* __restrict__ pr1, const float* __restrict__ pt1,
        const float* __restrict__ mr2, const float* __restrict__ mt2,
        const float* __restrict__ pr2, const float* __restrict__ pt2,
        float* __restrict__ w1, float* __restrict__ w2) {
    int e = blockIdx.x * blockDim.x + threadIdx.x;
    if (e >= E_) return;
    int n = e / K_;
    int b = n / N_;
    int fn = b * N_ + nbr_idx[e];
    float dx = centre[2*n]   - centre[2*fn];
    float dy = centre[2*n+1] - centre[2*fn+1];
    float rho   = sqrtf(dx*dx + dy*dy);
    float theta = atan2f(dx, dy);
    const float TWO_PI = 6.28318530717958647692f;
    {
        float w[R_]; float s = 0.f;
        #pragma unroll
        for (int r = 0; r < R_; ++r) {
            float dr = rho - mr1[r];
            float wr = expf(-0.5f * dr * dr / (1e-14f + pr1[r]*pr1[r]));
            float fa = fabsf(theta - mt1[r]);
            float mi = fminf(fa, fabsf(TWO_PI - fa));
            float wt = expf(-0.5f * mi * mi / (1e-14f + pt1[r]*pt1[r]));
            float ww = wr * wt;
            if (isnan(ww)) ww = 0.f;
            w[r] = ww; s += ww;
        }
        float gw = graph_w[e];
        float4 o0 = { gw*(w[0]/s), gw*(w[1]/s), gw*(w[2]/s), gw*(w[3]/s) };
        float4 o1 = { gw*(w[4]/s), gw*(w[5]/s), gw*(w[6]/s), gw*(w[7]/s) };
        *(float4*)&w1[e*R_]     = o0;
        *(float4*)&w1[e*R_ + 4] = o1;
    }
    {
        float w[R_]; float s = 0.f;
        #pragma unroll
        for (int r = 0; r < R_; ++r) {
            float dr = rho - mr2[r];
            float wr = expf(-0.5f * dr * dr / (1e-14f + pr2[r]*pr2[r]));
            float fa = fabsf(theta - mt2[r]);
            float mi = fminf(fa, fabsf(TWO_PI - fa));
            float wt = expf(-0.5f * mi * mi / (1e-14f + pt2[r]*pt2[r]));
            float ww = wr * wt;
            if (isnan(ww)) ww = 0.f;
            w[r] = ww; s += ww;
        }
        float4 o0 = { w[0]/s, w[1]/s, w[2]/s, w[3]/s };
        float4 o1 = { w[4]/s, w[5]/s, w[6]/s, w[7]/s };
        *(float4*)&w2[e*R_]     = o0;
        *(float4*)&w2[e*R_ + 4] = o1;
    }
}

// --------------------------------------------------------------------------
// X fp32 -> bf16 (vectorized)
// --------------------------------------------------------------------------
__global__ __launch_bounds__(256) void cast_x_kernel(
        const float* __restrict__ X, ushort* __restrict__ Xb) {
    int i = (blockIdx.x * 256 + threadIdx.x) * 4;
    float4 v = *(const float4*)&X[i];
    ushort4 o; o.x = f2bf(v.x); o.y = f2bf(v.y); o.z = f2bf(v.z); o.w = f2bf(v.w);
    *(ushort4*)&Xb[i] = o;
}

// --------------------------------------------------------------------------
// conv_w [8][1024][128] fp32 -> Wt[j][c] bf16 (j = r*128+d), LDS-tiled transpose.
// grid: (ctile=16, r=8, layer=2). Coalesced reads along d, coalesced writes
// along c. LDS stride 138 ushorts = 69 dwords (coprime 32) -> conflict-free.
// --------------------------------------------------------------------------
__global__ __launch_bounds__(256) void wtrans_kernel(
        const float* __restrict__ W1, ushort* __restrict__ Wt1,
        const float* __restrict__ W2, ushort* __restrict__ Wt2) {
    __shared__ ushort T[64][138];
    const float* W = (blockIdx.z == 0) ? W1 : W2;
    ushort*    Wt = (blockIdx.z == 0) ? Wt1 : Wt2;
    int r  = blockIdx.y;
    int c0 = blockIdx.x * 64;
    int t  = threadIdx.x;
    int lane6 = t & 63;
    #pragma unroll
    for (int it = 0; it < 16; ++it) {
        int ch = (t >> 6) + 4 * it;          // 0..63
        int d  = lane6 * 2;
        const float* src = &W[(((size_t)r << 10) + c0 + ch) * 128 + d];
        float2 v = *(const float2*)src;
        T[ch][d]     = f2bf(v.x);
        T[ch][d + 1] = f2bf(v.y);
    }
    __syncthreads();
    #pragma unroll
    for (int it = 0; it < 32; ++it) {
        int d = (t >> 6) + 4 * it;           // 0..127
        Wt[(size_t)(r * 128 + d) * 1024 + c0 + lane6] = T[lane6][d];
    }
}

// --------------------------------------------------------------------------
// bf16 MFMA GEMM: P[m][j] = sum_c Xb[m][c] * Wt[j][c].  M=6400,N=1024,K=1024.
// 128x128 tile, BK=32, 4 waves, 16x16x32 MFMA, global_load_lds w=16,
// LDS 16B-slot XOR swizzle, DOUBLE-BUFFERED: stage(t+1) -> compute(t) -> sync.
// --------------------------------------------------------------------------
__global__ __launch_bounds__(256) void gemm_bf16_kernel(
        const ushort* __restrict__ Xb,   // [6400][1024]
        const ushort* __restrict__ Wt,   // [1024][1024]
        ushort* __restrict__ P) {        // [6400][1024]
    __shared__ ushort As[2][128][32];
    __shared__ ushort Bs[2][128][32];
    int tile = blockIdx.x;                       // 400 = 8 XCDs * 50
    int swz  = (tile & 7) * 50 + (tile >> 3);    // bijective XCD chunking
    int m0 = (swz >> 3) * 128, n0 = (swz & 7) * 128;
    int t = threadIdx.x, wid = t >> 6, lane = t & 63;
    int wr = wid >> 1, wc = wid & 1;

    int srow  = lane >> 2;
    int sslot = (lane & 3) ^ ((lane >> 2) & 3) ^ (lane >> 4);
    int pslot = (lane >> 4) ^ (lane & 3) ^ ((lane >> 2) & 3);

    f32x4 acc[4][4];
    #pragma unroll
    for (int i = 0; i < 4; ++i)
        #pragma unroll
        for (int j = 0; j < 4; ++j) acc[i][j] = (f32x4)0.f;

    int arow = wr * 64 + (lane & 15);
    int brow = wc * 64 + (lane & 15);
    int rowblk0 = wid * 16, rowblk1 = (4 + wid) * 16;
    const ushort* agp = Xb + (size_t)(m0 + srow) * 1024 + sslot * 8;
    const ushort* bgp = Wt + (size_t)(n0 + srow) * 1024 + sslot * 8;

    // prologue: stage K-step 0 into buffer 0
    gload_lds16(agp + (size_t)rowblk0 * 1024, &As[0][rowblk0][0]);
    gload_lds16(bgp + (size_t)rowblk0 * 1024, &Bs[0][rowblk0][0]);
    gload_lds16(agp + (size_t)rowblk1 * 1024, &As[0][rowblk1][0]);
    gload_lds16(bgp + (size_t)rowblk1 * 1024, &Bs[0][rowblk1][0]);
    __syncthreads();

    for (int ts = 0; ts < 32; ++ts) {
        int cur = ts & 1;
        if (ts < 31) {
            int c1 = (ts + 1) * 32;
            gload_lds16(agp + (size_t)rowblk0 * 1024 + c1, &As[cur ^ 1][rowblk0][0]);
            gload_lds16(bgp + (size_t)rowblk0 * 1024 + c1, &Bs[cur ^ 1][rowblk0][0]);
            gload_lds16(agp + (size_t)rowblk1 * 1024 + c1, &As[cur ^ 1][rowblk1][0]);
            gload_lds16(bgp + (size_t)rowblk1 * 1024 + c1, &Bs[cur ^ 1][rowblk1][0]);
        }
        bf16x8 af[4], bfr[4];
        #pragma unroll
        for (int mi = 0; mi < 4; ++mi)
            af[mi] = *(const bf16x8*)&As[cur][arow + mi * 16][pslot * 8];
        #pragma unroll
        for (int ni = 0; ni < 4; ++ni)
            bfr[ni] = *(const bf16x8*)&Bs[cur][brow + ni * 16][pslot * 8];
        #pragma unroll
        for (int mi = 0; mi < 4; ++mi)
            #pragma unroll
            for (int ni = 0; ni < 4; ++ni)
                acc[mi][ni] = __builtin_amdgcn_mfma_f32_16x16x32_bf16(
                    af[mi], bfr[ni], acc[mi][ni], 0, 0, 0);
        __syncthreads();   // drains vmcnt (next buf ready) + syncs readers
    }
    // C/D: col = lane&15, row = (lane>>4)*4 + q   [m89-verified]
    int col = lane & 15, rq = lane >> 4;
    #pragma unroll
    for (int mi = 0; mi < 4; ++mi) {
        int row = m0 + wr * 64 + mi * 16 + rq * 4;
        #pragma unroll
        for (int ni = 0; ni < 4; ++ni) {
            int cc = n0 + wc * 64 + ni * 16 + col;
            #pragma unroll
            for (int q = 0; q < 4; ++q)
                P[(size_t)(row + q) * 1024 + cc] = f2bf(acc[mi][ni][q]);
        }
    }
}

// --------------------------------------------------------------------------
// out[n,j] = relu( sum_k w[nK+k, j>>7] * P[fnbr(n,k)][j] ); P bf16.
// 2 nodes per block, 16B gather loads.
// --------------------------------------------------------------------------
__global__ __launch_bounds__(256) void aggregate_kernel(
        const ushort* __restrict__ P, const float* __restrict__ w,
        const int* __restrict__ nbr_idx,
        ushort* __restrict__ outB, float* __restrict__ outF) {
    __shared__ float wv[2][K_][R_];
    __shared__ int fnbr[2][K_];
    int bid = blockIdx.x;                    // 3200 = 8 * 400, bijective
    int n0 = ((bid & 7) * 400 + (bid >> 3)) * 2;
    int t = threadIdx.x;
    {   // 256 weights = 2 nodes x 16 k x 8 r
        int node = t >> 7, rem = t & 127, k = rem >> 3, r = rem & 7;
        wv[node][k][r] = w[((size_t)(n0 + node) * K_ + k) * R_ + r];
    }
    if (t < 32) {
        int node = t >> 4, k = t & 15, nn = n0 + node;
        fnbr[node][k] = (nn / N_) * N_ + nbr_idx[nn * K_ + k];
    }
    __syncthreads();
    int node = t >> 7, jj = t & 127;
    int j0 = jj * 8;
    int r  = jj >> 4;
    float a[8] = {};
    #pragma unroll
    for (int k = 0; k < K_; ++k) {
        bf16x8 v = *(const bf16x8*)&P[(size_t)fnbr[node][k] * 1024 + j0];
        float wk = wv[node][k][r];
        #pragma unroll
        for (int q = 0; q < 8; ++q) a[q] += wk * bf2f((ushort)v[q]);
    }
    #pragma unroll
    for (int q = 0; q < 8; ++q) a[q] = fmaxf(a[q], 0.f);
    size_t base = (size_t)(n0 + node) * 1024 + j0;
    if (outB) {
        bf16x8 o;
        #pragma unroll
        for (int q = 0; q < 8; ++q) o[q] = (short)f2bf(a[q]);
        *(bf16x8*)&outB[base] = o;
    } else {
        float4 o0 = { a[0], a[1], a[2], a[3] };
        float4 o1 = { a[4], a[5], a[6], a[7] };
        *(float4*)&outF[base]     = o0;
        *(float4*)&outF[base + 4] = o1;
    }
}

// --------------------------------------------------------------------------
extern "C" void kernel_launch(void* const* d_in, const int* in_sizes, int n_in,
                              void* d_out, int out_size, void* d_ws, size_t ws_size,
                              hipStream_t stream) {
    const float* node_feats = (const float*)d_in[0];
    const float* centre     = (const float*)d_in[1];
    const float* graph_w    = (const float*)d_in[2];
    const int*   nbr_idx    = (const int*)  d_in[3];
    const float* mr1 = (const float*)d_in[4];
    const float* mt1 = (const float*)d_in[5];
    const float* pr1 = (const float*)d_in[6];
    const float* pt1 = (const float*)d_in[7];
    const float* cw1 = (const float*)d_in[8];
    const float* mr2 = (const float*)d_in[9];
    const float* mt2 = (const float*)d_in[10];
    const float* pr2 = (const float*)d_in[11];
    const float* pt2 = (const float*)d_in[12];
    const float* cw2 = (const float*)d_in[13];

    char* ws = (char*)d_ws;
    float*  w1  = (float*)ws;                 ws += (size_t)E_ * R_ * 4;
    float*  w2  = (float*)ws;                 ws += (size_t)E_ * R_ * 4;
    ushort* Xb  = (ushort*)ws;                ws += (size_t)BN_ * 1024 * 2;
    ushort* W1t = (ushort*)ws;                ws += (size_t)1024 * 1024 * 2;
    ushort* W2t = (ushort*)ws;                ws += (size_t)1024 * 1024 * 2;
    ushort* hb  = (ushort*)ws;                ws += (size_t)BN_ * 1024 * 2;
    ushort* P   = (ushort*)ws;

    float* out = (float*)d_out;

    edge_weights_kernel<<<(E_ + 255) / 256, 256, 0, stream>>>(
        centre, nbr_idx, graph_w, mr1, mt1, pr1, pt1, mr2, mt2, pr2, pt2, w1, w2);
    cast_x_kernel<<<BN_ * 1024 / 4 / 256, 256, 0, stream>>>(node_feats, Xb);
    wtrans_kernel<<<dim3(16, 8, 2), 256, 0, stream>>>(cw1, W1t, cw2, W2t);

    gemm_bf16_kernel<<<400, 256, 0, stream>>>(Xb, W1t, P);
    aggregate_kernel<<<BN_ / 2, 256, 0, stream>>>(P, w1, nbr_idx, hb, nullptr);

    gemm_bf16_kernel<<<400, 256, 0, stream>>>(hb, W2t, P);
    aggregate_kernel<<<BN_ / 2, 256, 0, stream>>>(P, w2, nbr_idx, nullptr, out);
}